// Round 10
// baseline (147.630 us; speedup 1.0000x reference)
//
#include <hip/hip_runtime.h>
#include <hip/hip_bf16.h>

// PNALayer: B=4, Nc=512, Nf=256, F_NHID=C_NHID=64, U_HID=U_OUT=128, M_INIT=1600, M_HID=256, M_OUT=64
// ALL I/O float32. R27 = R26 + prep2 ABSORBED into edge (each block redundantly computes its
// batch's avg_d/scale/sinv from wsDegC + degF partials: ~4.6K L2 loads + 3 logs/thread, folded
// into existing prologue barriers). 4 kernels instead of 5 -> one launch gap removed.

using bs8 = __attribute__((ext_vector_type(8))) short;   // 8 bf16 in 4 VGPRs (MFMA A/B frag)
using f4  = __attribute__((ext_vector_type(4))) float;   // MFMA C/D frag
using f2  = __attribute__((ext_vector_type(2))) float;   // packed f32 pair (v_pk_* ops)

__device__ __forceinline__ unsigned short f2bf(float f) {
    union { float f; unsigned int u; } x; x.f = f;
    unsigned int u = x.u + 0x7FFFu + ((x.u >> 16) & 1u);
    return (unsigned short)(u >> 16);
}

// packed pair via v_cvt_pk_bf16_f32 (compiler emits it from the _rn intrinsic)
__device__ __forceinline__ unsigned int pkbf(float a, float b) {
    __hip_bfloat162 h = __float22bfloat162_rn(make_float2(a, b));
    union { __hip_bfloat162 h; unsigned int u; } c; c.h = h;
    return c.u;
}

// Stub-parity symbol (harmless).
__global__ void PNALayer_35081292874189_kernel() {}

// ---------------- workspace layout (bytes) ----------------
#define OFF_AC     0u          // 2048*128 f32 = 1048576
#define OFF_AF     1048576u    // 1024*128 f32 = 524288
#define OFF_DEGC   1572864u    // 2048 f32
#define OFF_FEATB  1601536u    // 2048*1600 bf16 = 6553600 (+256 slack for K-pad overread)
#define OFF_HMID   8155392u    // 2048*256 f32   = 2097152
#define OFF_W2T    10252544u   // 128*128 bf16   = 32768 (U_W2^T, n-major, bf16)
#define OFF_W1TB   10318080u   // 256*1664 bf16  = 851968 (M_W1^T, n-major, K zero-padded to 1664)
#define OFF_DEGFP  11170048u   // 4*16*256 f32   = 65536 (degF partials: [b][chunk][f])
#define WS_NEED    11235584u

__global__ void PNALayer_ws_fail(float* out, int n) {
    int i = blockIdx.x * 256 + threadIdx.x;
    if (i < n) out[i] = 2500.0f;
}

// K1: A_c, A_f, degC, U_W2 transpose->bf16 (4), M_W1 transpose->bf16 (100), pad (1),
//     degF partials (64: 4 batches x 16 chunks of 32 customer rows, coalesced).
__global__ void PNALayer_prep1(
    const float* h_fac, const float* h_cus, const float* adj,
    const float* U_W1, const float* U_b1, const float* U_W2, const float* M_W1,
    float* wsAc, float* wsAf, float* wsDegC,
    unsigned short* wsW2Tb, unsigned short* wsW1Tb, float* wsDegFP)
{
    __shared__ float sH[64];
    __shared__ float sRed[256];
    __shared__ float sT[64][65];
    int bid = blockIdx.x, t = threadIdx.x;

    if (bid < 1024) {
        int b = bid >> 8, f = bid & 255;
        if (t < 64) sH[t] = h_fac[(b * 256 + f) * 64 + t];
        __syncthreads();
        if (t < 128) {
            float acc = 0.f;
            for (int k = 0; k < 64; ++k)
                acc += sH[k] * U_W1[(64 + k) * 128 + t];
            wsAf[(b * 256 + f) * 128 + t] = acc;
        }
    } else if (bid < 3072) {
        int bc = bid - 1024;
        if (t < 64) sH[t] = h_cus[bc * 64 + t];
        __syncthreads();
        if (t < 128) {
            float acc = U_b1[t];
            for (int k = 0; k < 64; ++k)
                acc += sH[k] * U_W1[k * 128 + t];
            wsAc[bc * 128 + t] = acc;
        }
        float v = adj[bc * 256 + t];
        sRed[t] = v; __syncthreads();
        for (int s = 128; s > 0; s >>= 1) { if (t < s) sRed[t] += sRed[t + s]; __syncthreads(); }
        if (t == 0) wsDegC[bc] = sRed[0];
    } else if (bid < 3076) {
        // transpose U_W2 [k][n] -> wsW2Tb [n][k] bf16, 64x64 tiles
        int l = bid - 3072;
        int k0 = (l >> 1) * 64, n0 = (l & 1) * 64;
        for (int rep = 0; rep < 16; ++rep) {
            int idx = rep * 256 + t; int r = idx >> 6, c = idx & 63;
            sT[r][c] = U_W2[(k0 + r) * 128 + n0 + c];
        }
        __syncthreads();
        for (int rep = 0; rep < 16; ++rep) {
            int idx = rep * 256 + t; int r = idx >> 6, c = idx & 63;
            wsW2Tb[(n0 + r) * 128 + k0 + c] = f2bf(sT[c][r]);
        }
    } else if (bid < 3176) {
        // transpose M_W1 [k][n] (1600x256) -> wsW1Tb [n][k] bf16, 64x64 tiles
        int l = bid - 3076;            // 0..99
        int k0 = (l % 25) * 64, n0 = (l / 25) * 64;
        for (int rep = 0; rep < 16; ++rep) {
            int idx = rep * 256 + t; int r = idx >> 6, c = idx & 63;
            sT[r][c] = M_W1[(k0 + r) * 256 + n0 + c];
        }
        __syncthreads();
        for (int rep = 0; rep < 16; ++rep) {
            int idx = rep * 256 + t; int r = idx >> 6, c = idx & 63;
            wsW1Tb[(n0 + r) * 1664 + k0 + c] = f2bf(sT[c][r]);
        }
    } else if (bid < 3177) {
        // zero the K-pad region k in [1600,1664) for all 256 n
        for (int i = 0; i < 64; ++i) {
            int idx = i * 256 + t;     // 0..16383
            int n = idx >> 6, k = 1600 + (idx & 63);
            wsW1Tb[n * 1664 + k] = 0;
        }
    } else {
        // degF partials: block (b, chunk) sums 32 customer rows, coalesced lanes over f
        int l = bid - 3177;            // 0..63
        int b = l >> 4, ch = l & 15;
        const float* ap = adj + (b * 512 + ch * 32) * 256 + t;
        float s = 0.f;
#pragma unroll 8
        for (int c = 0; c < 32; ++c)
            s += ap[c * 256];
        wsDegFP[(b * 16 + ch) * 256 + t] = s;
    }
}

// K2: per-(b,c) edge MLP via MFMA + masked aggregation -> featB row (1600, bf16)
// 4 waves x 256 threads; wave w owns cols [w*32, w*32+32) as two 16-col reg B-tiles.
// Prologue additionally computes the batch's avg_d/scale/sinv block-locally (absorbs prep2):
// 512 degC + 4096 degFP L2 loads, 3 logs/thread, wave-butterfly + LDS reduce — no extra barriers.
__global__ __launch_bounds__(256, 4) void PNALayer_edge(
    const float* h_cus, const float* edge, const float* adj,
    const float* U_W1, const float* U_b2,
    const float* wsAc, const float* wsAf, const unsigned short* wsW2Tb,
    const float* wsDegC, const float* wsDegFP,
    unsigned short* featB)
{
    __shared__ __align__(16) unsigned short sM1[64 * 136];
    __shared__ float sE[256];
    __shared__ float sAc[128];
    __shared__ float sWe[128];
    __shared__ unsigned short sFidx[256];
    __shared__ unsigned long long sBal[4];
    __shared__ float sWsum[4];

    int bc = blockIdx.x;
    int b  = bc >> 9;
    int t  = threadIdx.x;
    int w = t >> 6, quad = (t >> 4) & 3, ln = t & 15;

    // B fragments for this wave's two 16-col tiles, loaded once (global, L2-hit).
    int r0 = w * 32 + ln;
    int r1 = w * 32 + 16 + ln;
    bs8 bw0[4], bw1[4];
#pragma unroll
    for (int kk = 0; kk < 4; ++kk) {
        bw0[kk] = *(const bs8*)(wsW2Tb + r0 * 128 + kk * 32 + quad * 8);
        bw1[kk] = *(const bs8*)(wsW2Tb + r1 * 128 + kk * 32 + quad * 8);
    }
    float b2v0 = U_b2[r0], b2v1 = U_b2[r1];

    // Phase 1: masks + ballot, sE, sAc/sWe, h_cus featB slice (all within 256 threads)
    sE[t] = edge[bc * 256 + t];
    bool m = adj[bc * 256 + t] > 0.f;
    unsigned long long bal = __ballot(m);
    if ((t & 63) == 0) sBal[t >> 6] = bal;
    if (t < 128) {
        sAc[t] = wsAc[bc * 128 + t];
        sWe[t] = U_W1[128 * 128 + t];
    } else if (t < 192) {
        int j = t - 128;
        featB[bc * 1600 + j] = f2bf(h_cus[bc * 64 + j]);
    }
    __syncthreads();

    // Phase 2: compacted facility index list
    unsigned long long b0 = sBal[0], b1 = sBal[1], b2 = sBal[2], b3 = sBal[3];
    int cnt = __popcll(b0) + __popcll(b1) + __popcll(b2) + __popcll(b3);
    {
        int wv = t >> 6, l = t & 63;
        int base = 0;
        if (wv > 0) base += __popcll(b0);
        if (wv > 1) base += __popcll(b1);
        if (wv > 2) base += __popcll(b2);
        int rank = __popcll(bal & ((1ULL << l) - 1ULL));
        if (m) sFidx[base + rank] = (unsigned short)t;
    }

    // Phase 3a: batch avg_d partial (absorbed prep2). Each thread: 2 customer logs + 1 facility log.
    {
        float dc0 = wsDegC[b * 512 + t];
        float dc1 = wsDegC[b * 512 + 256 + t];
        float df = 0.f;
#pragma unroll
        for (int ch = 0; ch < 16; ++ch)
            df += wsDegFP[(b * 16 + ch) * 256 + t];
        float part = logf(dc0 + 1.f) + logf(dc1 + 1.f) + logf(df + 1.f);
#pragma unroll
        for (int off = 32; off > 0; off >>= 1)
            part += __shfl_xor(part, off, 64);
        if ((t & 63) == 0) sWsum[t >> 6] = part;
    }
    __syncthreads();   // sFidx + sWsum both ready

    // Phase 3b: scale/sinv for this customer (registers, uniform across block)
    float avgd = (sWsum[0] + sWsum[1] + sWsum[2] + sWsum[3]) / 768.f;
    float sc_  = logf((float)cnt + 1.f) / avgd;
    float si_  = (sc_ != 0.f) ? 1.f / sc_ : 0.f;

    int ntiles = (cnt + 63) >> 6;

    f2 aS0 = (f2){0.f, 0.f}, aQ0 = (f2){0.f, 0.f};
    f2 aMx0 = (f2){-1e30f, -1e30f}, aMn0 = (f2){1e30f, 1e30f};
    f2 aS1 = (f2){0.f, 0.f}, aQ1 = (f2){0.f, 0.f};
    f2 aMx1 = (f2){-1e30f, -1e30f}, aMn1 = (f2){1e30f, 1e30f};
    const f2 zero2 = (f2){0.f, 0.f};

    for (int tl = 0; tl < ntiles; ++tl) {
        // stage: relu(A_c + A_f + e*We) -> bf16 sM1 (64 compacted edges x 128 dims)
#pragma unroll
        for (int i = 0; i < 8; ++i) {
            int idx = i * 256 + t;
            int fl = idx >> 5, k = (idx & 31) * 4;
            int fj = tl * 64 + fl;
            uint2 p = make_uint2(0u, 0u);
            if (fj < cnt) {
                int f = sFidx[fj];
                float4 af  = *(const float4*)(wsAf + (b * 256 + f) * 128 + k);
                float4 ac4 = *(const float4*)(sAc + k);
                float4 we4 = *(const float4*)(sWe + k);
                float e = sE[f];
                f2 e2 = (f2){e, e};
                f2 s01 = (f2){ac4.x + af.x, ac4.y + af.y};
                f2 s23 = (f2){ac4.z + af.z, ac4.w + af.w};
                s01 = __builtin_elementwise_fma(e2, (f2){we4.x, we4.y}, s01);
                s23 = __builtin_elementwise_fma(e2, (f2){we4.z, we4.w}, s23);
                f2 r01 = __builtin_elementwise_max(s01, zero2);
                f2 r23 = __builtin_elementwise_max(s23, zero2);
                p.x = pkbf(r01.x, r01.y);
                p.y = pkbf(r23.x, r23.y);
            }
            *(uint2*)(sM1 + fl * 136 + k) = p;
        }
        __syncthreads();

        f4 acc0[4], acc1[4];
#pragma unroll
        for (int rt = 0; rt < 4; ++rt) {
            acc0[rt] = (f4){0.f, 0.f, 0.f, 0.f};
            acc1[rt] = (f4){0.f, 0.f, 0.f, 0.f};
        }
#pragma unroll
        for (int kk = 0; kk < 4; ++kk) {
            int ko = kk * 32 + quad * 8;
#pragma unroll
            for (int rt = 0; rt < 4; ++rt) {
                bs8 a = *(const bs8*)(sM1 + (rt * 16 + ln) * 136 + ko);
                acc0[rt] = __builtin_amdgcn_mfma_f32_16x16x32_bf16(a, bw0[kk], acc0[rt], 0, 0, 0);
                acc1[rt] = __builtin_amdgcn_mfma_f32_16x16x32_bf16(a, bw1[kk], acc1[rt], 0, 0, 0);
            }
        }

        if (((tl + 1) << 6) <= cnt) {
            // full tile: packed-f2 aggregation, no bound checks (2 elems/inst)
#pragma unroll
            for (int rt = 0; rt < 4; ++rt) {
                f2 p01 = (f2){acc0[rt][0], acc0[rt][1]};
                f2 p23 = (f2){acc0[rt][2], acc0[rt][3]};
                aS0 = aS0 + p01;
                aS0 = aS0 + p23;
                aQ0 = __builtin_elementwise_fma(p01, p01, aQ0);
                aQ0 = __builtin_elementwise_fma(p23, p23, aQ0);
                aMx0 = __builtin_elementwise_max(aMx0, __builtin_elementwise_max(p01, p23));
                aMn0 = __builtin_elementwise_min(aMn0, __builtin_elementwise_min(p01, p23));
                f2 q01 = (f2){acc1[rt][0], acc1[rt][1]};
                f2 q23 = (f2){acc1[rt][2], acc1[rt][3]};
                aS1 = aS1 + q01;
                aS1 = aS1 + q23;
                aQ1 = __builtin_elementwise_fma(q01, q01, aQ1);
                aQ1 = __builtin_elementwise_fma(q23, q23, aQ1);
                aMx1 = __builtin_elementwise_max(aMx1, __builtin_elementwise_max(q01, q23));
                aMn1 = __builtin_elementwise_min(aMn1, __builtin_elementwise_min(q01, q23));
            }
        } else {
            // boundary tile: scalar with bound check
#pragma unroll
            for (int rt = 0; rt < 4; ++rt) {
#pragma unroll
                for (int i = 0; i < 4; ++i) {
                    int fj = tl * 64 + rt * 16 + quad * 4 + i;
                    if (fj < cnt) {
                        float v0 = acc0[rt][i];
                        aS0.x += v0;
                        aQ0.x = fmaf(v0, v0, aQ0.x);
                        aMx0.x = fmaxf(aMx0.x, v0);
                        aMn0.x = fminf(aMn0.x, v0);
                        float v1 = acc1[rt][i];
                        aS1.x += v1;
                        aQ1.x = fmaf(v1, v1, aQ1.x);
                        aMx1.x = fmaxf(aMx1.x, v1);
                        aMn1.x = fminf(aMn1.x, v1);
                    }
                }
            }
        }
        __syncthreads();
    }

    float aS[2], aQ[2], aMx[2], aMn[2];
    aS[0] = aS0.x + aS0.y;  aQ[0] = aQ0.x + aQ0.y;
    aMx[0] = fmaxf(aMx0.x, aMx0.y);  aMn[0] = fminf(aMn0.x, aMn0.y);
    aS[1] = aS1.x + aS1.y;  aQ[1] = aQ1.x + aQ1.y;
    aMx[1] = fmaxf(aMx1.x, aMx1.y);  aMn[1] = fminf(aMn1.x, aMn1.y);

    // finish reduction across the 4 quads (rows live on lanes quad*16+ln)
#pragma unroll
    for (int ct = 0; ct < 2; ++ct) {
        aS[ct]  += __shfl_xor(aS[ct], 16, 64);  aS[ct]  += __shfl_xor(aS[ct], 32, 64);
        aQ[ct]  += __shfl_xor(aQ[ct], 16, 64);  aQ[ct]  += __shfl_xor(aQ[ct], 32, 64);
        aMx[ct] = fmaxf(aMx[ct], __shfl_xor(aMx[ct], 16, 64));
        aMx[ct] = fmaxf(aMx[ct], __shfl_xor(aMx[ct], 32, 64));
        aMn[ct] = fminf(aMn[ct], __shfl_xor(aMn[ct], 16, 64));
        aMn[ct] = fminf(aMn[ct], __shfl_xor(aMn[ct], 32, 64));
    }

    if (quad == 0) {
        float cntf = (float)cnt;
        unsigned short* fr = featB + bc * 1600;
        float b2[2] = {b2v0, b2v1};
#pragma unroll
        for (int ct = 0; ct < 2; ++ct) {
            int col = w * 32 + ct * 16 + ln;
            float meanr = aS[ct] / cntf;
            float mean  = meanr + b2[ct];                            // bias shift
            float var   = fmaxf(aQ[ct] / cntf - meanr * meanr, 0.f); // bias-invariant
            float stdv  = sqrtf(var);
            float mx = aMx[ct] + b2[ct], mn = aMn[ct] + b2[ct];
            fr[64 + col]   = f2bf(mean); fr[192 + col]  = f2bf(mean * sc_); fr[320 + col]  = f2bf(mean * si_);
            fr[448 + col]  = f2bf(stdv); fr[576 + col]  = f2bf(stdv * sc_); fr[704 + col]  = f2bf(stdv * si_);
            fr[832 + col]  = f2bf(mx);   fr[960 + col]  = f2bf(mx * sc_);   fr[1088 + col] = f2bf(mx * si_);
            fr[1216 + col] = f2bf(mn);   fr[1344 + col] = f2bf(mn * sc_);   fr[1472 + col] = f2bf(mn * si_);
        }
    }
}

// K3: h_mid = relu(featB @ W1Tb^T + b1) via MFMA. Block = 32 rows x 64 cols, 512 thr, grid 256.
// LDS: sA bf16[32][136]=8704B, sB bf16[64][136]=17408B  (26112 B total)
__global__ __launch_bounds__(512, 2) void PNALayer_mlp1(
    const unsigned short* featB, const unsigned short* wsW1Tb, const float* M_b1,
    float* h_mid)
{
    __shared__ __align__(16) unsigned short sA[32 * 136];
    __shared__ __align__(16) unsigned short sB[64 * 136];
    int t = threadIdx.x;
    int rb = (blockIdx.x >> 2) * 32, cb = (blockIdx.x & 3) * 64;
    int w = t >> 6, quad = (t >> 4) & 3, ln = t & 15;
    int wr = w >> 2, wc = w & 3;   // wave tile: rows [wr*16,+16), cols [wc*16,+16)

    f4 acc = (f4){0.f, 0.f, 0.f, 0.f};

    for (int kt = 0; kt < 13; ++kt) {
        int kb = kt * 128;
        {   // stage A: 32 rows x 128 k (512 uint4, 1/thread)
            int row = t >> 4, c8 = (t & 15) * 8;
            *(uint4*)(sA + row * 136 + c8) =
                *(const uint4*)(featB + (rb + row) * 1600 + kb + c8);
        }
#pragma unroll
        for (int i = 0; i < 2; ++i) {   // stage B: 64 n-rows x 128 k (1024 uint4, 2/thread)
            int vi = i * 512 + t;
            int row = vi >> 4, c8 = (vi & 15) * 8;
            *(uint4*)(sB + row * 136 + c8) =
                *(const uint4*)(wsW1Tb + (cb + row) * 1664 + kb + c8);
        }
        __syncthreads();
#pragma unroll
        for (int kk = 0; kk < 4; ++kk) {
            int ko = kk * 32 + quad * 8;
            bs8 a  = *(const bs8*)(sA + (wr * 16 + ln) * 136 + ko);
            bs8 bb = *(const bs8*)(sB + (wc * 16 + ln) * 136 + ko);
            acc = __builtin_amdgcn_mfma_f32_16x16x32_bf16(a, bb, acc, 0, 0, 0);
        }
        __syncthreads();
    }
    // C/D: col=ln (n), row=quad*4+i (m)
    int col = cb + wc * 16 + ln;
    float b1v = M_b1[col];
#pragma unroll
    for (int i = 0; i < 4; ++i) {
        int row = rb + wr * 16 + quad * 4 + i;
        h_mid[row * 256 + col] = fmaxf(acc[i] + b1v, 0.f);
    }
}

// K4: out = h_mid @ M_W2 + b2  (f32). LDS-staged rows: 8 rows/block, grid 256.
// h_mid reads fully coalesced (float4); each thread computes 2 outputs sharing W2 loads.
__global__ __launch_bounds__(256) void PNALayer_mlp2(
    const float* h_mid, const float* M_W2, const float* M_b2, float* out)
{
    __shared__ float sH[8 * 256];
    int t = threadIdx.x;
    int rb = blockIdx.x * 8;
#pragma unroll
    for (int i = 0; i < 2; ++i) {
        int vi = i * 256 + t;            // 0..511
        int row = vi >> 6, c4 = (vi & 63) * 4;
        *(float4*)(sH + row * 256 + c4) =
            *(const float4*)(h_mid + (rb + row) * 256 + c4);
    }
    __syncthreads();
    int j = t & 63, r = t >> 6;          // r in 0..3; this thread does rows r and r+4
    float acc0 = M_b2[j], acc1 = acc0;
    const float* h0 = sH + r * 256;
    const float* h1 = sH + (r + 4) * 256;
#pragma unroll 8
    for (int k = 0; k < 256; ++k) {
        float wv = M_W2[k * 64 + j];     // 64 lanes consecutive j -> coalesced 256B
        acc0 = fmaf(h0[k], wv, acc0);
        acc1 = fmaf(h1[k], wv, acc1);
    }
    out[(rb + r) * 64 + j] = acc0;
    out[(rb + r + 4) * 64 + j] = acc1;
}

extern "C" void kernel_launch(void* const* d_in, const int* in_sizes, int n_in,
                              void* d_out, int out_size, void* d_ws, size_t ws_size,
                              hipStream_t stream) {
    const float* h_fac = (const float*)d_in[0];
    const float* h_cus = (const float*)d_in[1];
    const float* edge  = (const float*)d_in[2];
    const float* adj   = (const float*)d_in[3];
    const float* U_W1  = (const float*)d_in[4];
    const float* U_b1  = (const float*)d_in[5];
    const float* U_W2  = (const float*)d_in[6];
    const float* U_b2  = (const float*)d_in[7];
    const float* M_W1  = (const float*)d_in[8];
    const float* M_b1  = (const float*)d_in[9];
    const float* M_W2  = (const float*)d_in[10];
    const float* M_b2  = (const float*)d_in[11];
    (void)in_sizes; (void)n_in;

    float* outp = (float*)d_out;
    int nblk_out = (out_size + 255) / 256;

    if (ws_size < (size_t)WS_NEED) {
        PNALayer_ws_fail<<<nblk_out, 256, 0, stream>>>(outp, out_size);
        return;
    }

    char* ws = (char*)d_ws;
    float*          wsAc   = (float*)(ws + OFF_AC);
    float*          wsAf   = (float*)(ws + OFF_AF);
    float*          wsDegC = (float*)(ws + OFF_DEGC);
    unsigned short* wsFeatB= (unsigned short*)(ws + OFF_FEATB);
    float*          wsHmid = (float*)(ws + OFF_HMID);
    unsigned short* wsW2Tb = (unsigned short*)(ws + OFF_W2T);
    unsigned short* wsW1Tb = (unsigned short*)(ws + OFF_W1TB);
    float*          wsDegFP= (float*)(ws + OFF_DEGFP);

    PNALayer_prep1<<<3241, 256, 0, stream>>>(
        h_fac, h_cus, adj, U_W1, U_b1, U_W2, M_W1,
        wsAc, wsAf, wsDegC, wsW2Tb, wsW1Tb, wsDegFP);
    PNALayer_edge<<<2048, 256, 0, stream>>>(
        h_cus, edge, adj, U_W1, U_b2,
        wsAc, wsAf, wsW2Tb, wsDegC, wsDegFP, wsFeatB);
    PNALayer_mlp1<<<256, 512, 0, stream>>>(wsFeatB, wsW1Tb, M_b1, wsHmid);
    PNALayer_mlp2<<<256, 256, 0, stream>>>(wsHmid, M_W2, M_b2, outp);
}

// Round 12
// 143.609 us; speedup vs baseline: 1.0280x; 1.0280x over previous
//
#include <hip/hip_runtime.h>
#include <hip/hip_bf16.h>

// PNALayer: B=4, Nc=512, Nf=256, F_NHID=C_NHID=64, U_HID=U_OUT=128, M_INIT=1600, M_HID=256, M_OUT=64
// ALL I/O float32. R29 = R28 resubmit (two infra failures; source identical to R26, verified
// 145.8us in round 9). Converged config. Ledger: compaction -8us (R20), degF parallel reduce
// -18us (R22), mlp2 coalesce -2us (R26); occupancy (R19), LDS-traffic (R23), dbuf (R25, spill),
// prep2-fusion (R27) all neutral-or-negative.

using bs8 = __attribute__((ext_vector_type(8))) short;   // 8 bf16 in 4 VGPRs (MFMA A/B frag)
using f4  = __attribute__((ext_vector_type(4))) float;   // MFMA C/D frag
using f2  = __attribute__((ext_vector_type(2))) float;   // packed f32 pair (v_pk_* ops)

__device__ __forceinline__ unsigned short f2bf(float f) {
    union { float f; unsigned int u; } x; x.f = f;
    unsigned int u = x.u + 0x7FFFu + ((x.u >> 16) & 1u);
    return (unsigned short)(u >> 16);
}

// packed pair via v_cvt_pk_bf16_f32 (compiler emits it from the _rn intrinsic)
__device__ __forceinline__ unsigned int pkbf(float a, float b) {
    __hip_bfloat162 h = __float22bfloat162_rn(make_float2(a, b));
    union { __hip_bfloat162 h; unsigned int u; } c; c.h = h;
    return c.u;
}

// Stub-parity symbol (harmless).
__global__ void PNALayer_35081292874189_kernel() {}

// ---------------- workspace layout (bytes) ----------------
#define OFF_AC     0u          // 2048*128 f32 = 1048576
#define OFF_AF     1048576u    // 1024*128 f32 = 524288
#define OFF_DEGC   1572864u    // 2048 f32
#define OFF_SCALE  1585152u    // 2048 f32
#define OFF_SINV   1593344u    // 2048 f32
#define OFF_FEATB  1601536u    // 2048*1600 bf16 = 6553600 (+256 slack for K-pad overread)
#define OFF_HMID   8155392u    // 2048*256 f32   = 2097152
#define OFF_W2T    10252544u   // 128*128 bf16   = 32768 (U_W2^T, n-major, bf16)
#define OFF_W1TB   10318080u   // 256*1664 bf16  = 851968 (M_W1^T, n-major, K zero-padded to 1664)
#define OFF_DEGFP  11170048u   // 4*16*256 f32   = 65536 (degF partials: [b][chunk][f])
#define WS_NEED    11235584u

__global__ void PNALayer_ws_fail(float* out, int n) {
    int i = blockIdx.x * 256 + threadIdx.x;
    if (i < n) out[i] = 2500.0f;
}

// K1: A_c, A_f, degC, U_W2 transpose->bf16 (4), M_W1 transpose->bf16 (100), pad (1),
//     degF partials (64: 4 batches x 16 chunks of 32 customer rows, coalesced).
__global__ void PNALayer_prep1(
    const float* h_fac, const float* h_cus, const float* adj,
    const float* U_W1, const float* U_b1, const float* U_W2, const float* M_W1,
    float* wsAc, float* wsAf, float* wsDegC,
    unsigned short* wsW2Tb, unsigned short* wsW1Tb, float* wsDegFP)
{
    __shared__ float sH[64];
    __shared__ float sRed[256];
    __shared__ float sT[64][65];
    int bid = blockIdx.x, t = threadIdx.x;

    if (bid < 1024) {
        int b = bid >> 8, f = bid & 255;
        if (t < 64) sH[t] = h_fac[(b * 256 + f) * 64 + t];
        __syncthreads();
        if (t < 128) {
            float acc = 0.f;
            for (int k = 0; k < 64; ++k)
                acc += sH[k] * U_W1[(64 + k) * 128 + t];
            wsAf[(b * 256 + f) * 128 + t] = acc;
        }
    } else if (bid < 3072) {
        int bc = bid - 1024;
        if (t < 64) sH[t] = h_cus[bc * 64 + t];
        __syncthreads();
        if (t < 128) {
            float acc = U_b1[t];
            for (int k = 0; k < 64; ++k)
                acc += sH[k] * U_W1[k * 128 + t];
            wsAc[bc * 128 + t] = acc;
        }
        float v = adj[bc * 256 + t];
        sRed[t] = v; __syncthreads();
        for (int s = 128; s > 0; s >>= 1) { if (t < s) sRed[t] += sRed[t + s]; __syncthreads(); }
        if (t == 0) wsDegC[bc] = sRed[0];
    } else if (bid < 3076) {
        // transpose U_W2 [k][n] -> wsW2Tb [n][k] bf16, 64x64 tiles
        int l = bid - 3072;
        int k0 = (l >> 1) * 64, n0 = (l & 1) * 64;
        for (int rep = 0; rep < 16; ++rep) {
            int idx = rep * 256 + t; int r = idx >> 6, c = idx & 63;
            sT[r][c] = U_W2[(k0 + r) * 128 + n0 + c];
        }
        __syncthreads();
        for (int rep = 0; rep < 16; ++rep) {
            int idx = rep * 256 + t; int r = idx >> 6, c = idx & 63;
            wsW2Tb[(n0 + r) * 128 + k0 + c] = f2bf(sT[c][r]);
        }
    } else if (bid < 3176) {
        // transpose M_W1 [k][n] (1600x256) -> wsW1Tb [n][k] bf16, 64x64 tiles
        int l = bid - 3076;            // 0..99
        int k0 = (l % 25) * 64, n0 = (l / 25) * 64;
        for (int rep = 0; rep < 16; ++rep) {
            int idx = rep * 256 + t; int r = idx >> 6, c = idx & 63;
            sT[r][c] = M_W1[(k0 + r) * 256 + n0 + c];
        }
        __syncthreads();
        for (int rep = 0; rep < 16; ++rep) {
            int idx = rep * 256 + t; int r = idx >> 6, c = idx & 63;
            wsW1Tb[(n0 + r) * 1664 + k0 + c] = f2bf(sT[c][r]);
        }
    } else if (bid < 3177) {
        // zero the K-pad region k in [1600,1664) for all 256 n
        for (int i = 0; i < 64; ++i) {
            int idx = i * 256 + t;     // 0..16383
            int n = idx >> 6, k = 1600 + (idx & 63);
            wsW1Tb[n * 1664 + k] = 0;
        }
    } else {
        // degF partials: block (b, chunk) sums 32 customer rows, coalesced lanes over f
        int l = bid - 3177;            // 0..63
        int b = l >> 4, ch = l & 15;
        const float* ap = adj + (b * 512 + ch * 32) * 256 + t;
        float s = 0.f;
#pragma unroll 8
        for (int c = 0; c < 32; ++c)
            s += ap[c * 256];
        wsDegFP[(b * 16 + ch) * 256 + t] = s;
    }
}

// K2: degF from 16 partials, avg_d, scale, scale_inv per batch. Grid 4.
__global__ void PNALayer_prep2(
    const float* wsDegFP, const float* wsDegC, float* wsScale, float* wsSinv)
{
    __shared__ float sRed[256];
    __shared__ float sAvg;
    int b = blockIdx.x, t = threadIdx.x;
    float df = 0.f;
#pragma unroll
    for (int ch = 0; ch < 16; ++ch)
        df += wsDegFP[(b * 16 + ch) * 256 + t];
    float v = logf(wsDegC[b * 512 + t] + 1.f) + logf(wsDegC[b * 512 + t + 256] + 1.f)
            + logf(df + 1.f);
    sRed[t] = v; __syncthreads();
    for (int s = 128; s > 0; s >>= 1) { if (t < s) sRed[t] += sRed[t + s]; __syncthreads(); }
    if (t == 0) sAvg = sRed[0] / 768.f;
    __syncthreads();
    float avg = sAvg;
    for (int c = t; c < 512; c += 256) {
        float lg = logf(wsDegC[b * 512 + c] + 1.f);
        float sc = lg / avg;
        float si = (sc != 0.f) ? 1.f / sc : 0.f;
        wsScale[b * 512 + c] = sc;
        wsSinv[b * 512 + c] = si;
    }
}

// K3: per-(b,c) edge MLP via MFMA + masked aggregation -> featB row (1600, bf16)
// 4 waves x 256 threads; wave w owns output cols [w*32, w*32+32) as two 16-col reg B-tiles.
// Single-buffer sM1, 2 barriers/tile (best measured structure).
__global__ __launch_bounds__(256, 4) void PNALayer_edge(
    const float* h_cus, const float* edge, const float* adj,
    const float* U_W1, const float* U_b2,
    const float* wsAc, const float* wsAf, const unsigned short* wsW2Tb,
    const float* wsScale, const float* wsSinv,
    unsigned short* featB)
{
    __shared__ __align__(16) unsigned short sM1[64 * 136];
    __shared__ float sE[256];
    __shared__ float sAc[128];
    __shared__ float sWe[128];
    __shared__ unsigned short sFidx[256];
    __shared__ unsigned long long sBal[4];

    int bc = blockIdx.x;
    int b  = bc >> 9;
    int t  = threadIdx.x;
    int w = t >> 6, quad = (t >> 4) & 3, ln = t & 15;

    // B fragments for this wave's two 16-col tiles, loaded once (global, L2-hit).
    int r0 = w * 32 + ln;
    int r1 = w * 32 + 16 + ln;
    bs8 bw0[4], bw1[4];
#pragma unroll
    for (int kk = 0; kk < 4; ++kk) {
        bw0[kk] = *(const bs8*)(wsW2Tb + r0 * 128 + kk * 32 + quad * 8);
        bw1[kk] = *(const bs8*)(wsW2Tb + r1 * 128 + kk * 32 + quad * 8);
    }
    float b2v0 = U_b2[r0], b2v1 = U_b2[r1];

    // Phase 1: masks + ballot, sE, sAc/sWe, h_cus featB slice (all within 256 threads)
    sE[t] = edge[bc * 256 + t];
    bool m = adj[bc * 256 + t] > 0.f;
    unsigned long long bal = __ballot(m);
    if ((t & 63) == 0) sBal[t >> 6] = bal;
    if (t < 128) {
        sAc[t] = wsAc[bc * 128 + t];
        sWe[t] = U_W1[128 * 128 + t];
    } else if (t < 192) {
        int j = t - 128;
        featB[bc * 1600 + j] = f2bf(h_cus[bc * 64 + j]);
    }
    __syncthreads();

    // Phase 2: compacted facility index list
    unsigned long long b0 = sBal[0], b1 = sBal[1], b2 = sBal[2], b3 = sBal[3];
    int cnt = __popcll(b0) + __popcll(b1) + __popcll(b2) + __popcll(b3);
    {
        int wv = t >> 6, l = t & 63;
        int base = 0;
        if (wv > 0) base += __popcll(b0);
        if (wv > 1) base += __popcll(b1);
        if (wv > 2) base += __popcll(b2);
        int rank = __popcll(bal & ((1ULL << l) - 1ULL));
        if (m) sFidx[base + rank] = (unsigned short)t;
    }
    __syncthreads();

    int ntiles = (cnt + 63) >> 6;

    f2 aS0 = (f2){0.f, 0.f}, aQ0 = (f2){0.f, 0.f};
    f2 aMx0 = (f2){-1e30f, -1e30f}, aMn0 = (f2){1e30f, 1e30f};
    f2 aS1 = (f2){0.f, 0.f}, aQ1 = (f2){0.f, 0.f};
    f2 aMx1 = (f2){-1e30f, -1e30f}, aMn1 = (f2){1e30f, 1e30f};
    const f2 zero2 = (f2){0.f, 0.f};

    for (int tl = 0; tl < ntiles; ++tl) {
        // stage: relu(A_c + A_f + e*We) -> bf16 sM1 (64 compacted edges x 128 dims)
#pragma unroll
        for (int i = 0; i < 8; ++i) {
            int idx = i * 256 + t;
            int fl = idx >> 5, k = (idx & 31) * 4;
            int fj = tl * 64 + fl;
            uint2 p = make_uint2(0u, 0u);
            if (fj < cnt) {
                int f = sFidx[fj];
                float4 af  = *(const float4*)(wsAf + (b * 256 + f) * 128 + k);
                float4 ac4 = *(const float4*)(sAc + k);
                float4 we4 = *(const float4*)(sWe + k);
                float e = sE[f];
                f2 e2 = (f2){e, e};
                f2 s01 = (f2){ac4.x + af.x, ac4.y + af.y};
                f2 s23 = (f2){ac4.z + af.z, ac4.w + af.w};
                s01 = __builtin_elementwise_fma(e2, (f2){we4.x, we4.y}, s01);
                s23 = __builtin_elementwise_fma(e2, (f2){we4.z, we4.w}, s23);
                f2 r01 = __builtin_elementwise_max(s01, zero2);
                f2 r23 = __builtin_elementwise_max(s23, zero2);
                p.x = pkbf(r01.x, r01.y);
                p.y = pkbf(r23.x, r23.y);
            }
            *(uint2*)(sM1 + fl * 136 + k) = p;
        }
        __syncthreads();

        f4 acc0[4], acc1[4];
#pragma unroll
        for (int rt = 0; rt < 4; ++rt) {
            acc0[rt] = (f4){0.f, 0.f, 0.f, 0.f};
            acc1[rt] = (f4){0.f, 0.f, 0.f, 0.f};
        }
#pragma unroll
        for (int kk = 0; kk < 4; ++kk) {
            int ko = kk * 32 + quad * 8;
#pragma unroll
            for (int rt = 0; rt < 4; ++rt) {
                bs8 a = *(const bs8*)(sM1 + (rt * 16 + ln) * 136 + ko);
                acc0[rt] = __builtin_amdgcn_mfma_f32_16x16x32_bf16(a, bw0[kk], acc0[rt], 0, 0, 0);
                acc1[rt] = __builtin_amdgcn_mfma_f32_16x16x32_bf16(a, bw1[kk], acc1[rt], 0, 0, 0);
            }
        }

        if (((tl + 1) << 6) <= cnt) {
            // full tile: packed-f2 aggregation, no bound checks (2 elems/inst)
#pragma unroll
            for (int rt = 0; rt < 4; ++rt) {
                f2 p01 = (f2){acc0[rt][0], acc0[rt][1]};
                f2 p23 = (f2){acc0[rt][2], acc0[rt][3]};
                aS0 = aS0 + p01;
                aS0 = aS0 + p23;
                aQ0 = __builtin_elementwise_fma(p01, p01, aQ0);
                aQ0 = __builtin_elementwise_fma(p23, p23, aQ0);
                aMx0 = __builtin_elementwise_max(aMx0, __builtin_elementwise_max(p01, p23));
                aMn0 = __builtin_elementwise_min(aMn0, __builtin_elementwise_min(p01, p23));
                f2 q01 = (f2){acc1[rt][0], acc1[rt][1]};
                f2 q23 = (f2){acc1[rt][2], acc1[rt][3]};
                aS1 = aS1 + q01;
                aS1 = aS1 + q23;
                aQ1 = __builtin_elementwise_fma(q01, q01, aQ1);
                aQ1 = __builtin_elementwise_fma(q23, q23, aQ1);
                aMx1 = __builtin_elementwise_max(aMx1, __builtin_elementwise_max(q01, q23));
                aMn1 = __builtin_elementwise_min(aMn1, __builtin_elementwise_min(q01, q23));
            }
        } else {
            // boundary tile: scalar with bound check
#pragma unroll
            for (int rt = 0; rt < 4; ++rt) {
#pragma unroll
                for (int i = 0; i < 4; ++i) {
                    int fj = tl * 64 + rt * 16 + quad * 4 + i;
                    if (fj < cnt) {
                        float v0 = acc0[rt][i];
                        aS0.x += v0;
                        aQ0.x = fmaf(v0, v0, aQ0.x);
                        aMx0.x = fmaxf(aMx0.x, v0);
                        aMn0.x = fminf(aMn0.x, v0);
                        float v1 = acc1[rt][i];
                        aS1.x += v1;
                        aQ1.x = fmaf(v1, v1, aQ1.x);
                        aMx1.x = fmaxf(aMx1.x, v1);
                        aMn1.x = fminf(aMn1.x, v1);
                    }
                }
            }
        }
        __syncthreads();
    }

    float aS[2], aQ[2], aMx[2], aMn[2];
    aS[0] = aS0.x + aS0.y;  aQ[0] = aQ0.x + aQ0.y;
    aMx[0] = fmaxf(aMx0.x, aMx0.y);  aMn[0] = fminf(aMn0.x, aMn0.y);
    aS[1] = aS1.x + aS1.y;  aQ[1] = aQ1.x + aQ1.y;
    aMx[1] = fmaxf(aMx1.x, aMx1.y);  aMn[1] = fminf(aMn1.x, aMn1.y);

    // finish reduction across the 4 quads (rows live on lanes quad*16+ln)
#pragma unroll
    for (int ct = 0; ct < 2; ++ct) {
        aS[ct]  += __shfl_xor(aS[ct], 16, 64);  aS[ct]  += __shfl_xor(aS[ct], 32, 64);
        aQ[ct]  += __shfl_xor(aQ[ct], 16, 64);  aQ[ct]  += __shfl_xor(aQ[ct], 32, 64);
        aMx[ct] = fmaxf(aMx[ct], __shfl_xor(aMx[ct], 16, 64));
        aMx[ct] = fmaxf(aMx[ct], __shfl_xor(aMx[ct], 32, 64));
        aMn[ct] = fminf(aMn[ct], __shfl_xor(aMn[ct], 16, 64));
        aMn[ct] = fminf(aMn[ct], __shfl_xor(aMn[ct], 32, 64));
    }

    if (quad == 0) {
        float cntf = (float)cnt;
        float sc = wsScale[bc], si = wsSinv[bc];
        unsigned short* fr = featB + bc * 1600;
        float b2[2] = {b2v0, b2v1};
#pragma unroll
        for (int ct = 0; ct < 2; ++ct) {
            int col = w * 32 + ct * 16 + ln;
            float meanr = aS[ct] / cntf;
            float mean  = meanr + b2[ct];                            // bias shift
            float var   = fmaxf(aQ[ct] / cntf - meanr * meanr, 0.f); // bias-invariant
            float stdv  = sqrtf(var);
            float mx = aMx[ct] + b2[ct], mn = aMn[ct] + b2[ct];
            fr[64 + col]   = f2bf(mean); fr[192 + col]  = f2bf(mean * sc); fr[320 + col]  = f2bf(mean * si);
            fr[448 + col]  = f2bf(stdv); fr[576 + col]  = f2bf(stdv * sc); fr[704 + col]  = f2bf(stdv * si);
            fr[832 + col]  = f2bf(mx);   fr[960 + col]  = f2bf(mx * sc);   fr[1088 + col] = f2bf(mx * si);
            fr[1216 + col] = f2bf(mn);   fr[1344 + col] = f2bf(mn * sc);   fr[1472 + col] = f2bf(mn * si);
        }
    }
}

// K4: h_mid = relu(featB @ W1Tb^T + b1) via MFMA. Block = 32 rows x 64 cols, 512 thr, grid 256.
// LDS: sA bf16[32][136]=8704B, sB bf16[64][136]=17408B  (26112 B total)
__global__ __launch_bounds__(512, 2) void PNALayer_mlp1(
    const unsigned short* featB, const unsigned short* wsW1Tb, const float* M_b1,
    float* h_mid)
{
    __shared__ __align__(16) unsigned short sA[32 * 136];
    __shared__ __align__(16) unsigned short sB[64 * 136];
    int t = threadIdx.x;
    int rb = (blockIdx.x >> 2) * 32, cb = (blockIdx.x & 3) * 64;
    int w = t >> 6, quad = (t >> 4) & 3, ln = t & 15;
    int wr = w >> 2, wc = w & 3;   // wave tile: rows [wr*16,+16), cols [wc*16,+16)

    f4 acc = (f4){0.f, 0.f, 0.f, 0.f};

    for (int kt = 0; kt < 13; ++kt) {
        int kb = kt * 128;
        {   // stage A: 32 rows x 128 k (512 uint4, 1/thread)
            int row = t >> 4, c8 = (t & 15) * 8;
            *(uint4*)(sA + row * 136 + c8) =
                *(const uint4*)(featB + (rb + row) * 1600 + kb + c8);
        }
#pragma unroll
        for (int i = 0; i < 2; ++i) {   // stage B: 64 n-rows x 128 k (1024 uint4, 2/thread)
            int vi = i * 512 + t;
            int row = vi >> 4, c8 = (vi & 15) * 8;
            *(uint4*)(sB + row * 136 + c8) =
                *(const uint4*)(wsW1Tb + (cb + row) * 1664 + kb + c8);
        }
        __syncthreads();
#pragma unroll
        for (int kk = 0; kk < 4; ++kk) {
            int ko = kk * 32 + quad * 8;
            bs8 a  = *(const bs8*)(sA + (wr * 16 + ln) * 136 + ko);
            bs8 bb = *(const bs8*)(sB + (wc * 16 + ln) * 136 + ko);
            acc = __builtin_amdgcn_mfma_f32_16x16x32_bf16(a, bb, acc, 0, 0, 0);
        }
        __syncthreads();
    }
    // C/D: col=ln (n), row=quad*4+i (m)
    int col = cb + wc * 16 + ln;
    float b1v = M_b1[col];
#pragma unroll
    for (int i = 0; i < 4; ++i) {
        int row = rb + wr * 16 + quad * 4 + i;
        h_mid[row * 256 + col] = fmaxf(acc[i] + b1v, 0.f);
    }
}

// K5: out = h_mid @ M_W2 + b2  (f32). LDS-staged rows: 8 rows/block, grid 256.
// h_mid reads fully coalesced (float4); each thread computes 2 outputs sharing W2 loads.
__global__ __launch_bounds__(256) void PNALayer_mlp2(
    const float* h_mid, const float* M_W2, const float* M_b2, float* out)
{
    __shared__ float sH[8 * 256];
    int t = threadIdx.x;
    int rb = blockIdx.x * 8;
#pragma unroll
    for (int i = 0; i < 2; ++i) {
        int vi = i * 256 + t;            // 0..511
        int row = vi >> 6, c4 = (vi & 63) * 4;
        *(float4*)(sH + row * 256 + c4) =
            *(const float4*)(h_mid + (rb + row) * 256 + c4);
    }
    __syncthreads();
    int j = t & 63, r = t >> 6;          // r in 0..3; this thread does rows r and r+4
    float acc0 = M_b2[j], acc1 = acc0;
    const float* h0 = sH + r * 256;
    const float* h1 = sH + (r + 4) * 256;
#pragma unroll 8
    for (int k = 0; k < 256; ++k) {
        float wv = M_W2[k * 64 + j];     // 64 lanes consecutive j -> coalesced 256B
        acc0 = fmaf(h0[k], wv, acc0);
        acc1 = fmaf(h1[k], wv, acc1);
    }
    out[(rb + r) * 64 + j] = acc0;
    out[(rb + r + 4) * 64 + j] = acc1;
}

extern "C" void kernel_launch(void* const* d_in, const int* in_sizes, int n_in,
                              void* d_out, int out_size, void* d_ws, size_t ws_size,
                              hipStream_t stream) {
    const float* h_fac = (const float*)d_in[0];
    const float* h_cus = (const float*)d_in[1];
    const float* edge  = (const float*)d_in[2];
    const float* adj   = (const float*)d_in[3];
    const float* U_W1  = (const float*)d_in[4];
    const float* U_b1  = (const float*)d_in[5];
    const float* U_W2  = (const float*)d_in[6];
    const float* U_b2  = (const float*)d_in[7];
    const float* M_W1  = (const float*)d_in[8];
    const float* M_b1  = (const float*)d_in[9];
    const float* M_W2  = (const float*)d_in[10];
    const float* M_b2  = (const float*)d_in[11];
    (void)in_sizes; (void)n_in;

    float* outp = (float*)d_out;
    int nblk_out = (out_size + 255) / 256;

    if (ws_size < (size_t)WS_NEED) {
        PNALayer_ws_fail<<<nblk_out, 256, 0, stream>>>(outp, out_size);
        return;
    }

    char* ws = (char*)d_ws;
    float*          wsAc   = (float*)(ws + OFF_AC);
    float*          wsAf   = (float*)(ws + OFF_AF);
    float*          wsDegC = (float*)(ws + OFF_DEGC);
    float*          wsScal = (float*)(ws + OFF_SCALE);
    float*          wsSinv = (float*)(ws + OFF_SINV);
    unsigned short* wsFeatB= (unsigned short*)(ws + OFF_FEATB);
    float*          wsHmid = (float*)(ws + OFF_HMID);
    unsigned short* wsW2Tb = (unsigned short*)(ws + OFF_W2T);
    unsigned short* wsW1Tb = (unsigned short*)(ws + OFF_W1TB);
    float*          wsDegFP= (float*)(ws + OFF_DEGFP);

    PNALayer_prep1<<<3241, 256, 0, stream>>>(
        h_fac, h_cus, adj, U_W1, U_b1, U_W2, M_W1,
        wsAc, wsAf, wsDegC, wsW2Tb, wsW1Tb, wsDegFP);
    PNALayer_prep2<<<4, 256, 0, stream>>>(wsDegFP, wsDegC, wsScal, wsSinv);
    PNALayer_edge<<<2048, 256, 0, stream>>>(
        h_cus, edge, adj, U_W1, U_b2,
        wsAc, wsAf, wsW2Tb, wsScal, wsSinv, wsFeatB);
    PNALayer_mlp1<<<256, 512, 0, stream>>>(wsFeatB, wsW1Tb, M_b1, wsHmid);
    PNALayer_mlp2<<<256, 256, 0, stream>>>(wsHmid, M_W2, M_b2, outp);
}